// Round 3
// baseline (761.646 us; speedup 1.0000x reference)
//
#include <hip/hip_runtime.h>

#define Bn 16
#define Cn 20
#define Hn 512
#define Wn 512
#define HWn (Hn*Wn)
#define Rr 16          // output rows per block
#define NA1 (Rr+3)     // a1 rows h0-1 .. h0+R+1
#define NA2 (Rr+1)     // a2 rows h0   .. h0+R

typedef float nfloat4 __attribute__((ext_vector_type(4)));

// Branchless step value: I[r] = a? (p[r-1] + (bb? p[r+1]:0)) : (bb? p[r+1] : p[r])
__device__ __forceinline__ float sv(float pm, float pc, float pp, int a, int bb) {
    float t  = bb ? pp : 0.0f;
    float v1 = pm + t;
    float v2 = bb ? pp : pc;
    return a ? v1 : v2;
}

__global__ __launch_bounds__(256, 4) void fused_kernel(const float* __restrict__ world,
                                                       float* __restrict__ out) {
    __shared__ unsigned char  sa1[NA1][Wn];   // 9728 B
    __shared__ unsigned char  sa2[NA2][Wn];   // 8704 B
    __shared__ unsigned short sco[Rr][Wn];    // 16384 B packed coeffs (5 x 2-bit)

    // XCD swizzle: give each XCD a contiguous chunk of (b, hgroup) space.
    int bid = blockIdx.x;                      // 1024 blocks
    int v   = (bid >> 3) | ((bid & 7) << 7);
    int chalf = v & 1;                         // which 10 channels
    int hg    = (v >> 1) & 31;
    int b     = v >> 6;
    int h0    = hg * Rr;
    int tid   = threadIdx.x;

    const float* base = world + (size_t)b * Cn * HWn;
    const float* e = base;            // channel 0 (element ids)
    const float* d = base + HWn;      // channel 1 (density)

    // ---- phase 1: a1 for rows h0-1 .. h0+R+1 ----
    // a1[r,w] = (e[r,w]==3) & (d[r,w-1]-d[r,w]>=0) & (d[r-1,w]-d[r,w]<0) & (d[r-1,w-1]-d[r,w]<0)
    for (int col = 0; col < 2; ++col) {
        int w  = tid + col * 256;
        int wm = (w - 1) & (Wn - 1);
        int r0 = (h0 - 2) & (Hn - 1);
        float dmw = d[r0 * Wn + w];
        float dmm = d[r0 * Wn + wm];
#pragma unroll
        for (int i = 0; i < NA1; ++i) {
            int r = (h0 - 1 + i) & (Hn - 1);
            float dc = d[r * Wn + w];
            float df = d[r * Wn + wm];
            float ec = e[r * Wn + w];
            bool a = (ec == 3.0f) & (df - dc >= 0.0f) & (dmw - dc < 0.0f) & (dmm - dc < 0.0f);
            sa1[i][w] = (unsigned char)a;
            dmw = dc; dmm = df;
        }
    }
    __syncthreads();

    // ---- phase 2: a2 for rows h0 .. h0+R ----
    // a2[h,w] = (I0[h,w]==3) & (I1[h,w+1]-I1[h,w]>=0) & (I1[h-1,w]-I1[h,w]<0) & (I1[h-1,w+1]-I1[h,w]<0)
    for (int col = 0; col < 2; ++col) {
        int w  = tid + col * 256;
        int wp = (w + 1) & (Wn - 1);
        // windows: dw* = d rows r-2..r+1 at w; dp* at w+1; ew* = e rows r-1..r+1 at w
        float dwa = d[((h0 - 2) & (Hn - 1)) * Wn + w];
        float dwb = d[((h0 - 1) & (Hn - 1)) * Wn + w];
        float dwc = d[h0 * Wn + w];
        float dwd = d[((h0 + 1) & (Hn - 1)) * Wn + w];
        float dpa = d[((h0 - 2) & (Hn - 1)) * Wn + wp];
        float dpb = d[((h0 - 1) & (Hn - 1)) * Wn + wp];
        float dpc = d[h0 * Wn + wp];
        float dpd = d[((h0 + 1) & (Hn - 1)) * Wn + wp];
        float ewa = e[((h0 - 1) & (Hn - 1)) * Wn + w];
        float ewb = e[h0 * Wn + w];
        float ewc = e[((h0 + 1) & (Hn - 1)) * Wn + w];
#pragma unroll
        for (int i2 = 0; i2 < NA2; ++i2) {
            int a_hm = sa1[i2][w],  a_h = sa1[i2 + 1][w],  a_hp = sa1[i2 + 2][w];
            int b_hm = sa1[i2][wp], b_h = sa1[i2 + 1][wp], b_hp = sa1[i2 + 2][wp];
            float I0   = sv(ewa, ewb, ewc, a_h, a_hp);
            float I1c  = sv(dwb, dwc, dwd, a_h, a_hp);
            float I1f  = sv(dpb, dpc, dpd, b_h, b_hp);
            float I1a  = sv(dwa, dwb, dwc, a_hm, a_h);
            float I1fa = sv(dpa, dpb, dpc, b_hm, b_h);
            bool av = (I0 == 3.0f) & (I1f - I1c >= 0.0f) & (I1a - I1c < 0.0f) & (I1fa - I1c < 0.0f);
            sa2[i2][w] = (unsigned char)av;
            int rn = (h0 + i2 + 2) & (Hn - 1);
            dwa = dwb; dwb = dwc; dwc = dwd; dwd = d[rn * Wn + w];
            dpa = dpb; dpb = dpc; dpc = dpd; dpd = d[rn * Wn + wp];
            ewa = ewb; ewb = ewc; ewc = e[rn * Wn + w];
        }
    }
    __syncthreads();

    // ---- phase 2.5: packed composite coefficients per output row (values in {0,1,2}) ----
#pragma unroll
    for (int k = 0; k < 32; ++k) {
        int idx = k * 256 + tid;
        int j2 = idx >> 9;
        int w  = idx & (Wn - 1);
        int rm1 = sa1[j2][w], r0v = sa1[j2 + 1][w], rp1 = sa1[j2 + 2][w], rp2 = sa1[j2 + 3][w];
        int s0 = sa2[j2][w], s1 = sa2[j2 + 1][w];
        int z  = (1 - s0) * (1 - s1);
        int cm2 = s0 * rm1;
        int cm1 = s0 * (1 - rm1) * (1 - r0v) + z * r0v;
        int c0  = s0 * r0v + z * (1 - r0v) * (1 - rp1) + s1 * rp1;
        int cp1 = z * rp1 + s1 * (1 - rp1) * (1 - rp2);
        int cp2 = s1 * rp2;
        sco[j2][w] = (unsigned short)(cm2 | (cm1 << 2) | (c0 << 4) | (cp1 << 6) | (cp2 << 8));
    }
    __syncthreads();

    // ---- phase 3: apply 5-row stencil to 10 channels, 8 rows per thread ----
    int wq = tid & 127;
    int rh = tid >> 7;
    int w  = wq * 4;
    int j0 = rh * 8;                       // output rows h0+j0 .. h0+j0+7
    float* obase = out + (size_t)b * Cn * HWn;
    int cstart = chalf * 10;

    for (int c = cstart; c < cstart + 10; ++c) {
        const float* p = base + (size_t)c * HWn;
        nfloat4 x[12];
#pragma unroll
        for (int i = 0; i < 12; ++i) {
            int r = (h0 + j0 - 2 + i) & (Hn - 1);
            x[i] = *(const nfloat4*)(p + r * Wn + w);
        }
        float* op = obase + (size_t)c * HWn + (size_t)(h0 + j0) * Wn + w;
#pragma unroll
        for (int j = 0; j < 8; ++j) {
            int j2 = j0 + j;
            uint2 q = *(const uint2*)&sco[j2][w];
            unsigned qa = q.x & 0xffffu;
            unsigned qb = q.x >> 16;
            unsigned qc = q.y & 0xffffu;
            unsigned qd = q.y >> 16;
            nfloat4 r4;
            r4.x = (float)(qa & 3) * x[j].x + (float)((qa >> 2) & 3) * x[j + 1].x
                 + (float)((qa >> 4) & 3) * x[j + 2].x + (float)((qa >> 6) & 3) * x[j + 3].x
                 + (float)((qa >> 8) & 3) * x[j + 4].x;
            r4.y = (float)(qb & 3) * x[j].y + (float)((qb >> 2) & 3) * x[j + 1].y
                 + (float)((qb >> 4) & 3) * x[j + 2].y + (float)((qb >> 6) & 3) * x[j + 3].y
                 + (float)((qb >> 8) & 3) * x[j + 4].y;
            r4.z = (float)(qc & 3) * x[j].z + (float)((qc >> 2) & 3) * x[j + 1].z
                 + (float)((qc >> 4) & 3) * x[j + 2].z + (float)((qc >> 6) & 3) * x[j + 3].z
                 + (float)((qc >> 8) & 3) * x[j + 4].z;
            r4.w = (float)(qd & 3) * x[j].w + (float)((qd >> 2) & 3) * x[j + 1].w
                 + (float)((qd >> 4) & 3) * x[j + 2].w + (float)((qd >> 6) & 3) * x[j + 3].w
                 + (float)((qd >> 8) & 3) * x[j + 4].w;
            __builtin_nontemporal_store(r4, (nfloat4*)(op + j * Wn));
        }
    }
}

extern "C" void kernel_launch(void* const* d_in, const int* in_sizes, int n_in,
                              void* d_out, int out_size, void* d_ws, size_t ws_size,
                              hipStream_t stream) {
    const float* world = (const float*)d_in[0];   // (16,20,512,512) fp32; rand_* unused
    float* out = (float*)d_out;
    fused_kernel<<<Bn * (Hn / Rr) * 2, 256, 0, stream>>>(world, out);
}